// Round 11
// baseline (658.687 us; speedup 1.0000x reference)
//
#include <hip/hip_runtime.h>
#include <hip/hip_bf16.h>

#define N_NODES 100000
#define N_EDGES 3200000
#define IN_DIM  128
#define HID     32
#define NCLUS   30
#define SCAN_CHUNK 1024
#define SCAN_NBLK  98   // ceil(100000/1024)
#define NSPLIT 8        // split counter copies (contention reduction)

__device__ __forceinline__ float bf2f(__hip_bfloat16 v) { return __bfloat162float(v); }

// dot of two packed-bf16 words (2 elems each), exact in fp32
__device__ __forceinline__ float dotw(unsigned a, unsigned b) {
  float r;
  r  = __uint_as_float(a << 16)          * __uint_as_float(b << 16);
  r += __uint_as_float(a & 0xffff0000u)  * __uint_as_float(b & 0xffff0000u);
  return r;
}

// edge_index accessor: f=0 -> int32 layout, f=1 -> int64 layout (read low word)
__device__ __forceinline__ int edge_at(const int* ei, int row, int e, int f) {
  int v = ei[(row * N_EDGES + e) << f];
  return min(max(v, 0), N_NODES - 1);
}

// ---- detect int32 vs int64 edge_index ----
__global__ void k_detect(const unsigned int* ei, int* flag) {
  if (threadIdx.x == 0) {
    int zeros = 0;
    for (int i = 1; i < 128; i += 2) zeros += (ei[i] == 0u) ? 1 : 0;
    *flag = (zeros >= 48) ? 1 : 0;
  }
}

// ---- zero init (loss scalars only; cntc zeroed via memset) ----
__global__ void k_zero(float* colsum, double* msed) {
  int t = blockIdx.x * blockDim.x + threadIdx.x;
  if (t < 32) colsum[t] = 0.0f;
  if (t == 32) *msed = 0.0;
}

// ---- split count + per-edge rank: c = blockIdx&7 picks the counter copy ----
__global__ void k_countrank8(const int* ei, const int* flag, int* cntc, int* rank) {
  int e = blockIdx.x * blockDim.x + threadIdx.x;
  if (e >= N_EDGES) return;
  int f = *flag;
  int d = edge_at(ei, 1, e, f);
  int c = blockIdx.x & (NSPLIT - 1);
  rank[e] = atomicAdd(&cntc[c * N_NODES + d], 1);
}

// ---- merge copies: cnt[n] = total; cntc[c][n] <- exclusive prefix over copies ----
__global__ void k_merge(int* cntc, int* cnt) {
  int n = blockIdx.x * blockDim.x + threadIdx.x;
  if (n >= N_NODES) return;
  int run = 0;
  #pragma unroll
  for (int c = 0; c < NSPLIT; c++) {
    int t = cntc[c * N_NODES + n];
    cntc[c * N_NODES + n] = run;
    run += t;
  }
  cnt[n] = run;
}

// ---- plain count (fallback path) ----
__global__ void k_count(const int* ei, const int* flag, int* cnt) {
  int e = blockIdx.x * blockDim.x + threadIdx.x;
  if (e >= N_EDGES) return;
  int f = *flag;
  atomicAdd(&cnt[edge_at(ei, 1, e, f)], 1);
}

__global__ void k_zerocnt(int* cnt) {
  int t = blockIdx.x * blockDim.x + threadIdx.x;
  if (t < N_NODES) cnt[t] = 0;
}

// ---- dinv ----
__global__ void k_dinv(const int* cnt, float* dinv) {
  int t = blockIdx.x * blockDim.x + threadIdx.x;
  if (t < N_NODES) dinv[t] = rsqrtf((float)(cnt[t] + 1));
}

// ---- scan stage 1 ----
__global__ void k_scan1(const int* cnt, int* bsum) {
  __shared__ int sd[256];
  int tid = threadIdx.x;
  int base = blockIdx.x * SCAN_CHUNK;
  int s = 0;
  for (int i = tid; i < SCAN_CHUNK; i += 256) {
    int idx = base + i;
    s += (idx < N_NODES) ? cnt[idx] : 0;
  }
  sd[tid] = s; __syncthreads();
  for (int off = 128; off > 0; off >>= 1) {
    if (tid < off) sd[tid] += sd[tid + off];
    __syncthreads();
  }
  if (tid == 0) bsum[blockIdx.x] = sd[0];
}

// ---- scan stage 2 ----
__global__ void k_scan2(int* bsum) {
  if (threadIdx.x == 0) {
    int run = 0;
    for (int i = 0; i < SCAN_NBLK; i++) { int t = bsum[i]; bsum[i] = run; run += t; }
  }
}

// ---- scan stage 3: cursor = exclusive prefix (row START) ----
__global__ void k_scan3(const int* cnt, const int* bsum, int* cursor) {
  __shared__ int ts[256];
  int tid = threadIdx.x;
  int base = blockIdx.x * SCAN_CHUNK + tid * 4;
  int v[4]; int s = 0;
  #pragma unroll
  for (int j = 0; j < 4; j++) {
    int idx = base + j;
    v[j] = (idx < N_NODES) ? cnt[idx] : 0;
    s += v[j];
  }
  ts[tid] = s; __syncthreads();
  for (int off = 1; off < 256; off <<= 1) {
    int t = (tid >= off) ? ts[tid - off] : 0;
    __syncthreads();
    ts[tid] += t;
    __syncthreads();
  }
  int excl = bsum[blockIdx.x] + (tid > 0 ? ts[tid - 1] : 0);
  #pragma unroll
  for (int j = 0; j < 4; j++) {
    int idx = base + j;
    if (idx < N_NODES) { cursor[idx] = excl; excl += v[j]; }
  }
}

// ---- CSR scatter, atomic-free, split-rank: pos = cursor[d] + copyprefix + rank ----
__global__ void k_scatter3(const int* ei, const int* flag, const int* cursor,
                           const int* cntc, const int* rank, int* csr_src) {
  int e = blockIdx.x * blockDim.x + threadIdx.x;
  if (e >= N_EDGES) return;
  int f = *flag;
  int s = edge_at(ei, 0, e, f);
  int d = edge_at(ei, 1, e, f);
  int c = blockIdx.x & (NSPLIT - 1);   // same grid config as k_countrank8 -> same c
  csr_src[cursor[d] + cntc[c * N_NODES + d] + rank[e]] = s;
}

// ---- GEMM1 scaled -> bf16 ----
__global__ void __launch_bounds__(256) k_gemm1b(const float* x, const float* W1,
                                                const float* dinv, __hip_bfloat16* G1) {
  __shared__ float Ws[IN_DIM * HID];
  int tid = threadIdx.x;
  for (int i = tid; i < IN_DIM * HID; i += 256) Ws[i] = W1[i];
  __syncthreads();
  int j = tid & 31, r = tid >> 5;
  int n = blockIdx.x * 8 + r;
  if (n >= N_NODES) return;
  const float* xr = x + (size_t)n * IN_DIM;
  float acc = 0.0f;
  #pragma unroll
  for (int k = 0; k < IN_DIM; k++) acc += xr[k] * Ws[k * HID + j];
  G1[n * 32 + j] = __float2bfloat16(acc * dinv[n]);
}

// ---- CSR agg layer1 (bf16 gather) ----
__global__ void __launch_bounds__(256) k_agg1b(const __hip_bfloat16* G, const int* cursor,
                                               const int* cnt, const int* csr, const float* dinv,
                                               const float* b1, float* h) {
  int j = threadIdx.x & 31, g = threadIdx.x >> 5;
  int n = blockIdx.x * 8 + g;
  if (n >= N_NODES) return;
  int len = cnt[n];
  int st = cursor[n];
  float acc = bf2f(G[n * 32 + j]);
  int i = 0;
  for (; i + 4 <= len; i += 4) {
    int s0 = csr[st + i], s1 = csr[st + i + 1], s2 = csr[st + i + 2], s3 = csr[st + i + 3];
    float v0 = bf2f(G[s0 * 32 + j]), v1 = bf2f(G[s1 * 32 + j]);
    float v2 = bf2f(G[s2 * 32 + j]), v3 = bf2f(G[s3 * 32 + j]);
    acc += (v0 + v1) + (v2 + v3);
  }
  for (; i < len; i++) acc += bf2f(G[csr[st + i] * 32 + j]);
  h[n * 32 + j] = fmaxf(dinv[n] * acc + b1[j], 0.0f);
}

// ---- GEMM2 scaled -> bf16; cols 30,31 = 0 ----
__global__ void __launch_bounds__(256) k_gemm2b(const float* h, const float* W2,
                                                const float* dinv, __hip_bfloat16* G2) {
  __shared__ float Ws[HID * 32];
  int tid = threadIdx.x;
  for (int i = tid; i < HID * 32; i += 256) Ws[i] = 0.0f;
  __syncthreads();
  for (int i = tid; i < HID * NCLUS; i += 256) {
    int k = i / NCLUS, j = i % NCLUS;
    Ws[k * 32 + j] = W2[i];
  }
  __syncthreads();
  int j = tid & 31, r = tid >> 5;
  int n = blockIdx.x * 8 + r;
  if (n >= N_NODES) return;
  const float* hr = h + (size_t)n * 32;
  float acc = 0.0f;
  #pragma unroll
  for (int k = 0; k < HID; k++) acc += hr[k] * Ws[k * 32 + j];
  G2[n * 32 + j] = __float2bfloat16((j < NCLUS) ? acc * dinv[n] : 0.0f);
}

// ---- CSR agg layer2 (bf16 gather) + softmax -> out (fp32) + fx16 (bf16, 32-padded) ----
__global__ void __launch_bounds__(256) k_agg2b(const __hip_bfloat16* G, const int* cursor,
                                               const int* cnt, const int* csr, const float* dinv,
                                               const float* b2, float* outp, __hip_bfloat16* fx16) {
  int j = threadIdx.x & 31, g = threadIdx.x >> 5;
  int n = blockIdx.x * 8 + g;
  if (n >= N_NODES) return;
  int len = cnt[n];
  int st = cursor[n];
  float acc = bf2f(G[n * 32 + j]);
  int i = 0;
  for (; i + 4 <= len; i += 4) {
    int s0 = csr[st + i], s1 = csr[st + i + 1], s2 = csr[st + i + 2], s3 = csr[st + i + 3];
    float v0 = bf2f(G[s0 * 32 + j]), v1 = bf2f(G[s1 * 32 + j]);
    float v2 = bf2f(G[s2 * 32 + j]), v3 = bf2f(G[s3 * 32 + j]);
    acc += (v0 + v1) + (v2 + v3);
  }
  for (; i < len; i++) acc += bf2f(G[csr[st + i] * 32 + j]);
  bool act = (j < NCLUS);
  float logit = act ? fminf(fmaxf(dinv[n] * acc + b2[j], -80.0f), 80.0f) : -1e30f;
  float m = logit;
  #pragma unroll
  for (int mask = 16; mask > 0; mask >>= 1) m = fmaxf(m, __shfl_xor(m, mask, 32));
  float ex = act ? __expf(logit - m) : 0.0f;
  float ssum = ex;
  #pragma unroll
  for (int mask = 16; mask > 0; mask >>= 1) ssum += __shfl_xor(ssum, mask, 32);
  float fx = ex / fmaxf(ssum, 1e-30f);
  if (act) outp[n * NCLUS + j] = fx;
  fx16[n * 32 + j] = __float2bfloat16(act ? fx : 0.0f);
}

// ---- fallback fp32 kernels (atomic path) ----
__global__ void __launch_bounds__(256) k_gemm1s(const float* x, const float* W1,
                                                const float* dinv, float* G1) {
  __shared__ float Ws[IN_DIM * HID];
  int tid = threadIdx.x;
  for (int i = tid; i < IN_DIM * HID; i += 256) Ws[i] = W1[i];
  __syncthreads();
  int j = tid & 31, r = tid >> 5;
  int n = blockIdx.x * 8 + r;
  if (n >= N_NODES) return;
  const float* xr = x + (size_t)n * IN_DIM;
  float acc = 0.0f;
  #pragma unroll
  for (int k = 0; k < IN_DIM; k++) acc += xr[k] * Ws[k * HID + j];
  G1[n * 32 + j] = acc * dinv[n];
}

__global__ void __launch_bounds__(256) k_gemm2s(const float* h, const float* W2,
                                                const float* dinv, float* G2) {
  __shared__ float Ws[HID * 32];
  int tid = threadIdx.x;
  for (int i = tid; i < HID * 32; i += 256) Ws[i] = 0.0f;
  __syncthreads();
  for (int i = tid; i < HID * NCLUS; i += 256) {
    int k = i / NCLUS, j = i % NCLUS;
    Ws[k * 32 + j] = W2[i];
  }
  __syncthreads();
  int j = tid & 31, r = tid >> 5;
  int n = blockIdx.x * 8 + r;
  if (n >= N_NODES) return;
  const float* hr = h + (size_t)n * 32;
  float acc = 0.0f;
  #pragma unroll
  for (int k = 0; k < HID; k++) acc += hr[k] * Ws[k * 32 + j];
  G2[n * 32 + j] = (j < NCLUS) ? acc * dinv[n] : 0.0f;
}

__global__ void __launch_bounds__(256) k_eagg2(const int* ei, const int* flag,
                                               const float* G, float* D) {
  int j = threadIdx.x & 31, g = threadIdx.x >> 5;
  int f = *flag;
  for (int e = blockIdx.x * 8 + g; e < N_EDGES; e += gridDim.x * 8) {
    int s = edge_at(ei, 0, e, f);
    int d = edge_at(ei, 1, e, f);
    atomicAdd(&D[d * 32 + j], G[s * 32 + j]);
  }
}

__global__ void k_relu2(const float* A, const float* dinv, const float* b1, float* G) {
  int t = blockIdx.x * blockDim.x + threadIdx.x;
  if (t >= N_NODES * 32) return;
  int n = t >> 5, j = t & 31;
  G[t] = fmaxf(dinv[n] * (A[t] + G[t]) + b1[j], 0.0f);
}

__global__ void __launch_bounds__(256) k_softmax2(const float* S, const float* G2, const float* dinv,
                                                  const float* b2, float* outp) {
  int n = blockIdx.x * blockDim.x + threadIdx.x;
  if (n >= N_NODES) return;
  float di = dinv[n];
  float lg[NCLUS];
  float m = -1e30f;
  #pragma unroll
  for (int j = 0; j < NCLUS; j++) {
    float v = di * (S[n * 32 + j] + G2[n * 32 + j]) + b2[j];
    v = fminf(fmaxf(v, -80.0f), 80.0f);
    lg[j] = v; m = fmaxf(m, v);
  }
  float ssum = 0.0f;
  #pragma unroll
  for (int j = 0; j < NCLUS; j++) { lg[j] = __expf(lg[j] - m); ssum += lg[j]; }
  float inv = 1.0f / ssum;
  #pragma unroll
  for (int j = 0; j < NCLUS; j++) outp[n * NCLUS + j] = lg[j] * inv;
}

// ---- out (fp32, stride 30) -> fx16 (bf16, stride 32) ----
__global__ void k_fx16(const float* outp, __hip_bfloat16* fx16) {
  int t = blockIdx.x * blockDim.x + threadIdx.x;
  if (t >= N_NODES * 32) return;
  int n = t >> 5, j = t & 31;
  fx16[t] = __float2bfloat16((j < NCLUS) ? outp[n * NCLUS + j] : 0.0f);
}

// ---- edge MSE, lane-per-edge: in-lane packed-bf16 dot over 64B rows ----
__global__ void __launch_bounds__(256) k_msef2(const int* ei, const float* ep,
                                               const uint4* fx16, const int* flag,
                                               double* msed) {
  int f = *flag;
  int tid = blockIdx.x * blockDim.x + threadIdx.x;
  float local = 0.0f;
  for (int e = tid; e < N_EDGES; e += gridDim.x * blockDim.x) {
    int s = edge_at(ei, 0, e, f);
    int d = edge_at(ei, 1, e, f);
    const uint4* rs = fx16 + s * 4;
    const uint4* rd = fx16 + d * 4;
    uint4 a0 = rs[0], a1 = rs[1], a2 = rs[2], a3 = rs[3];
    uint4 b0 = rd[0], b1 = rd[1], b2 = rd[2], b3 = rd[3];
    float acc;
    acc  = dotw(a0.x, b0.x) + dotw(a0.y, b0.y) + dotw(a0.z, b0.z) + dotw(a0.w, b0.w);
    acc += dotw(a1.x, b1.x) + dotw(a1.y, b1.y) + dotw(a1.z, b1.z) + dotw(a1.w, b1.w);
    acc += dotw(a2.x, b2.x) + dotw(a2.y, b2.y) + dotw(a2.z, b2.z) + dotw(a2.w, b2.w);
    acc += dotw(a3.x, b3.x) + dotw(a3.y, b3.y) + dotw(a3.z, b3.z) + dotw(a3.w, b3.w);
    float diff = acc - ep[e];
    local += diff * diff;
  }
  __shared__ float sd[256];
  sd[threadIdx.x] = local; __syncthreads();
  for (int off = 128; off > 0; off >>= 1) {
    if (threadIdx.x < off) sd[threadIdx.x] += sd[threadIdx.x + off];
    __syncthreads();
  }
  if (threadIdx.x == 0) atomicAdd(msed, (double)sd[0]);
}

// ---- column sums of log(1-FX^2) ----
__global__ void __launch_bounds__(256) k_colsumf(const float* FX, float* colsum) {
  __shared__ float sd[256];
  int tid = threadIdx.x;
  int j = tid & 31, g = tid >> 5;
  float local = 0.0f;
  if (j < NCLUS) {
    for (int n = blockIdx.x * 8 + g; n < N_NODES; n += gridDim.x * 8) {
      float v = FX[n * NCLUS + j];
      local += log1pf(-v * v);
    }
  }
  sd[tid] = local; __syncthreads();
  if (tid < 32) {
    float s = 0.0f;
    #pragma unroll
    for (int gg = 0; gg < 8; gg++) s += sd[tid + 32 * gg];
    if (tid < NCLUS) atomicAdd(&colsum[tid], s);
  }
}

// ---- final loss ----
__global__ void k_final(const float* colsum, const double* msed, float* out) {
  int tid = threadIdx.x;
  float v = 0.0f;
  if (tid < NCLUS) v = logf(1.0001f - __expf(colsum[tid]));
  #pragma unroll
  for (int mask = 32; mask > 0; mask >>= 1) v += __shfl_xor(v, mask, 64);
  if (tid == 0) {
    float preg = -v;
    float msev = (float)(*msed / (double)N_EDGES);
    out[(size_t)N_NODES * NCLUS] = msev + 0.01f * preg;
  }
}

extern "C" void kernel_launch(void* const* d_in, const int* in_sizes, int n_in,
                              void* d_out, int out_size, void* d_ws, size_t ws_size,
                              hipStream_t stream) {
  const float* x  = (const float*)d_in[0];
  const int*   ei = (const int*)d_in[1];
  const float* ep = (const float*)d_in[2];
  const float* W1 = (const float*)d_in[3];
  const float* b1 = (const float*)d_in[4];
  const float* W2 = (const float*)d_in[5];
  const float* b2 = (const float*)d_in[6];
  float* out = (float*)d_out;   // fp32: FX[100000*30] then loss scalar

  char* ws = (char*)d_ws;
  size_t off = 0;
  auto alloc = [&](size_t bytes) { size_t o = off; off += (bytes + 255) & ~(size_t)255; return o; };

  size_t o_hdr  = alloc(1024);                       // flag@0, msed@8(double), colsum@256, bsum@512
  size_t o_cnt  = alloc((size_t)N_NODES * 4);
  size_t o_dinv = alloc((size_t)N_NODES * 4);
  size_t o_B1   = alloc((size_t)N_NODES * 32 * 4);   // CSR: cntc (3.2MB) -> G1b/G2b (bf16) ; fallback: fp32 G
  size_t o_B2   = alloc((size_t)N_NODES * 32 * 4);   // CSR: rank -> h fp32 -> fx16 ; fallback: fp32 D

  int*    flag   = (int*)(ws + o_hdr);
  double* msed   = (double*)(ws + o_hdr + 8);
  float*  colsum = (float*)(ws + o_hdr + 256);
  int*    bsum   = (int*)(ws + o_hdr + 512);
  int*    cnt    = (int*)(ws + o_cnt);
  float*  dinv   = (float*)(ws + o_dinv);
  float*  B1f    = (float*)(ws + o_B1);
  float*  B2f    = (float*)(ws + o_B2);
  __hip_bfloat16* B1b = (__hip_bfloat16*)(ws + o_B1);
  __hip_bfloat16* B2b = (__hip_bfloat16*)(ws + o_B2);

  const int nodeBlocks = (N_NODES + 255) / 256;
  const int edgeBlocks = (N_EDGES + 255) / 256;
  const int grpBlocks  = (N_NODES + 7) / 8;
  const int elemBlocks = (N_NODES * 32 + 255) / 256;

  k_detect<<<1, 64, 0, stream>>>((const unsigned int*)ei, flag);

  size_t o_cursor = alloc((size_t)N_NODES * 4);
  size_t o_csr    = alloc((size_t)N_EDGES * 4);
  bool use_csr = (off <= ws_size);   // confirmed running since R7 (ws >= 40.3 MB)

  const __hip_bfloat16* fx16;

  if (use_csr) {
    int* cursor = (int*)(ws + o_cursor);
    int* csr    = (int*)(ws + o_csr);
    int* rank   = (int*)(ws + o_B2);   // dead until agg1b writes h
    int* cntc   = (int*)(ws + o_B1);   // 8*N ints = 3.2MB; dead until gemm1b writes G1

    k_zero<<<1, 64, 0, stream>>>(colsum, msed);
    hipMemsetAsync(cntc, 0, (size_t)NSPLIT * N_NODES * 4, stream);
    k_countrank8<<<edgeBlocks, 256, 0, stream>>>(ei, flag, cntc, rank);
    k_merge<<<nodeBlocks, 256, 0, stream>>>(cntc, cnt);
    k_dinv<<<nodeBlocks, 256, 0, stream>>>(cnt, dinv);
    k_scan1<<<SCAN_NBLK, 256, 0, stream>>>(cnt, bsum);
    k_scan2<<<1, 64, 0, stream>>>(bsum);
    k_scan3<<<SCAN_NBLK, 256, 0, stream>>>(cnt, bsum, cursor);
    k_scatter3<<<edgeBlocks, 256, 0, stream>>>(ei, flag, cursor, cntc, rank, csr);

    __hip_bfloat16* G1b  = B1b;        // overwrites cntc (dead after scatter3)
    float*          h    = B2f;        // overwrites rank (dead after scatter3)
    __hip_bfloat16* G2b  = B1b;
    __hip_bfloat16* fx   = B2b;

    k_gemm1b<<<grpBlocks, 256, 0, stream>>>(x, W1, dinv, G1b);
    k_agg1b<<<grpBlocks, 256, 0, stream>>>(G1b, cursor, cnt, csr, dinv, b1, h);
    k_gemm2b<<<grpBlocks, 256, 0, stream>>>(h, W2, dinv, G2b);
    k_agg2b<<<grpBlocks, 256, 0, stream>>>(G2b, cursor, cnt, csr, dinv, b2, out, fx);
    fx16 = fx;
  } else {
    k_zero<<<1, 64, 0, stream>>>(colsum, msed);
    k_zerocnt<<<nodeBlocks, 256, 0, stream>>>(cnt);
    k_count<<<edgeBlocks, 256, 0, stream>>>(ei, flag, cnt);
    k_dinv<<<nodeBlocks, 256, 0, stream>>>(cnt, dinv);
    k_gemm1s<<<grpBlocks, 256, 0, stream>>>(x, W1, dinv, B1f);
    hipMemsetAsync(B2f, 0, (size_t)N_NODES * 32 * 4, stream);
    k_eagg2<<<8192, 256, 0, stream>>>(ei, flag, B1f, B2f);
    k_relu2<<<elemBlocks, 256, 0, stream>>>(B2f, dinv, b1, B1f);
    k_gemm2s<<<grpBlocks, 256, 0, stream>>>(B1f, W2, dinv, B2f);
    hipMemsetAsync(B1f, 0, (size_t)N_NODES * 32 * 4, stream);
    k_eagg2<<<8192, 256, 0, stream>>>(ei, flag, B2f, B1f);
    k_softmax2<<<nodeBlocks, 256, 0, stream>>>(B1f, B2f, dinv, b2, out);
    k_fx16<<<elemBlocks, 256, 0, stream>>>(out, B1b);
    fx16 = B1b;
  }

  // loss
  k_msef2<<<4096, 256, 0, stream>>>(ei, ep, (const uint4*)fx16, flag, msed);
  k_colsumf<<<256, 256, 0, stream>>>(out, colsum);
  k_final<<<1, 64, 0, stream>>>(colsum, msed, out);
}

// Round 12
// 645.504 us; speedup vs baseline: 1.0204x; 1.0204x over previous
//
#include <hip/hip_runtime.h>
#include <hip/hip_bf16.h>

#define N_NODES 100000
#define N_EDGES 3200000
#define IN_DIM  128
#define HID     32
#define NCLUS   30
#define SCAN_CHUNK 1024
#define SCAN_NBLK  98     // ceil(100000/1024)
#define EDGE_BLOCKS 12500 // ceil(3200000/256)
#define GRP_BLOCKS  12500 // ceil(100000/8)

__device__ __forceinline__ float bf2f(__hip_bfloat16 v) { return __bfloat162float(v); }

// dot of two packed-bf16 words (2 elems each), exact in fp32
__device__ __forceinline__ float dotw(unsigned a, unsigned b) {
  float r;
  r  = __uint_as_float(a << 16)          * __uint_as_float(b << 16);
  r += __uint_as_float(a & 0xffff0000u)  * __uint_as_float(b & 0xffff0000u);
  return r;
}

// edge_index accessor: f=0 -> int32 layout, f=1 -> int64 layout (read low word)
__device__ __forceinline__ int edge_at(const int* ei, int row, int e, int f) {
  int v = ei[(row * N_EDGES + e) << f];
  return min(max(v, 0), N_NODES - 1);
}

// ---- detect int32 vs int64 edge_index ----
__global__ void k_detect(const unsigned int* ei, int* flag) {
  if (threadIdx.x == 0) {
    int zeros = 0;
    for (int i = 1; i < 128; i += 2) zeros += (ei[i] == 0u) ? 1 : 0;
    *flag = (zeros >= 48) ? 1 : 0;
  }
}

// ---- zero loss scalars ----
__global__ void k_zero(float* colsum, double* msed) {
  int t = blockIdx.x * blockDim.x + threadIdx.x;
  if (t < 32) colsum[t] = 0.0f;
  if (t == 32) *msed = 0.0;
}

__global__ void k_zerocnt(int* cnt) {
  int t = blockIdx.x * blockDim.x + threadIdx.x;
  if (t < N_NODES) cnt[t] = 0;
}

// ---- FUSED: blocks [0,EDGE_BLOCKS) do count+rank (atomic-stall-bound);
//      blocks [EDGE_BLOCKS, EDGE_BLOCKS+GRP_BLOCKS) do unscaled GEMM1 (VALU/mem-bound).
//      The two halves co-schedule on the device, hiding gemm1 inside the atomic drain. ----
__global__ void __launch_bounds__(256) k_fused1(const int* ei, const int* flag, int* cnt, int* rank,
                                                const float* x, const float* W1, __hip_bfloat16* G1) {
  __shared__ float Ws[IN_DIM * HID];   // 16 KB (used by gemm half only)
  if (blockIdx.x < EDGE_BLOCKS) {
    int e = blockIdx.x * 256 + threadIdx.x;
    if (e < N_EDGES) {
      int f = *flag;
      int d = edge_at(ei, 1, e, f);
      rank[e] = atomicAdd(&cnt[d], 1);
    }
    return;
  }
  int tid = threadIdx.x;
  for (int i = tid; i < IN_DIM * HID; i += 256) Ws[i] = W1[i];
  __syncthreads();
  int j = tid & 31, r = tid >> 5;
  int n = (blockIdx.x - EDGE_BLOCKS) * 8 + r;
  if (n >= N_NODES) return;
  const float* xr = x + (size_t)n * IN_DIM;
  float acc = 0.0f;
  #pragma unroll
  for (int k = 0; k < IN_DIM; k++) acc += xr[k] * Ws[k * HID + j];
  G1[n * 32 + j] = __float2bfloat16(acc);   // UNSCALED (dinv applied at gather)
}

// ---- plain count (fallback path) ----
__global__ void k_count(const int* ei, const int* flag, int* cnt) {
  int e = blockIdx.x * blockDim.x + threadIdx.x;
  if (e >= N_EDGES) return;
  int f = *flag;
  atomicAdd(&cnt[edge_at(ei, 1, e, f)], 1);
}

// ---- dinv ----
__global__ void k_dinv(const int* cnt, float* dinv) {
  int t = blockIdx.x * blockDim.x + threadIdx.x;
  if (t < N_NODES) dinv[t] = rsqrtf((float)(cnt[t] + 1));
}

// ---- scan stage 1 ----
__global__ void k_scan1(const int* cnt, int* bsum) {
  __shared__ int sd[256];
  int tid = threadIdx.x;
  int base = blockIdx.x * SCAN_CHUNK;
  int s = 0;
  for (int i = tid; i < SCAN_CHUNK; i += 256) {
    int idx = base + i;
    s += (idx < N_NODES) ? cnt[idx] : 0;
  }
  sd[tid] = s; __syncthreads();
  for (int off = 128; off > 0; off >>= 1) {
    if (tid < off) sd[tid] += sd[tid + off];
    __syncthreads();
  }
  if (tid == 0) bsum[blockIdx.x] = sd[0];
}

// ---- scan stage 2 ----
__global__ void k_scan2(int* bsum) {
  if (threadIdx.x == 0) {
    int run = 0;
    for (int i = 0; i < SCAN_NBLK; i++) { int t = bsum[i]; bsum[i] = run; run += t; }
  }
}

// ---- scan stage 3: cursor = exclusive prefix (row START) ----
__global__ void k_scan3(const int* cnt, const int* bsum, int* cursor) {
  __shared__ int ts[256];
  int tid = threadIdx.x;
  int base = blockIdx.x * SCAN_CHUNK + tid * 4;
  int v[4]; int s = 0;
  #pragma unroll
  for (int j = 0; j < 4; j++) {
    int idx = base + j;
    v[j] = (idx < N_NODES) ? cnt[idx] : 0;
    s += v[j];
  }
  ts[tid] = s; __syncthreads();
  for (int off = 1; off < 256; off <<= 1) {
    int t = (tid >= off) ? ts[tid - off] : 0;
    __syncthreads();
    ts[tid] += t;
    __syncthreads();
  }
  int excl = bsum[blockIdx.x] + (tid > 0 ? ts[tid - 1] : 0);
  #pragma unroll
  for (int j = 0; j < 4; j++) {
    int idx = base + j;
    if (idx < N_NODES) { cursor[idx] = excl; excl += v[j]; }
  }
}

// ---- CSR scatter, atomic-free ----
__global__ void k_scatter2(const int* ei, const int* flag, const int* cursor,
                           const int* rank, int* csr_src) {
  int e = blockIdx.x * blockDim.x + threadIdx.x;
  if (e >= N_EDGES) return;
  int f = *flag;
  int s = edge_at(ei, 0, e, f);
  int d = edge_at(ei, 1, e, f);
  csr_src[cursor[d] + rank[e]] = s;
}

// ---- CSR agg layer1, unroll-8, dinv[s]-weighted gather (G1 unscaled) ----
__global__ void __launch_bounds__(256) k_agg1c(const __hip_bfloat16* G, const int* cursor,
                                               const int* cnt, const int* csr, const float* dinv,
                                               const float* b1, float* h) {
  int j = threadIdx.x & 31, g = threadIdx.x >> 5;
  int n = blockIdx.x * 8 + g;
  if (n >= N_NODES) return;
  int len = cnt[n];
  int st = cursor[n];
  float dn = dinv[n];
  float acc = bf2f(G[n * 32 + j]) * dn;   // self loop
  int i = 0;
  for (; i + 8 <= len; i += 8) {
    int s[8];
    #pragma unroll
    for (int q = 0; q < 8; q++) s[q] = csr[st + i + q];
    float v[8], w[8];
    #pragma unroll
    for (int q = 0; q < 8; q++) { v[q] = bf2f(G[s[q] * 32 + j]); w[q] = dinv[s[q]]; }
    #pragma unroll
    for (int q = 0; q < 8; q++) acc += v[q] * w[q];
  }
  for (; i < len; i++) { int s0 = csr[st + i]; acc += bf2f(G[s0 * 32 + j]) * dinv[s0]; }
  h[n * 32 + j] = fmaxf(dn * acc + b1[j], 0.0f);
}

// ---- GEMM2 scaled -> bf16; cols 30,31 = 0 ----
__global__ void __launch_bounds__(256) k_gemm2b(const float* h, const float* W2,
                                                const float* dinv, __hip_bfloat16* G2) {
  __shared__ float Ws[HID * 32];
  int tid = threadIdx.x;
  for (int i = tid; i < HID * 32; i += 256) Ws[i] = 0.0f;
  __syncthreads();
  for (int i = tid; i < HID * NCLUS; i += 256) {
    int k = i / NCLUS, j = i % NCLUS;
    Ws[k * 32 + j] = W2[i];
  }
  __syncthreads();
  int j = tid & 31, r = tid >> 5;
  int n = blockIdx.x * 8 + r;
  if (n >= N_NODES) return;
  const float* hr = h + (size_t)n * 32;
  float acc = 0.0f;
  #pragma unroll
  for (int k = 0; k < HID; k++) acc += hr[k] * Ws[k * 32 + j];
  G2[n * 32 + j] = __float2bfloat16((j < NCLUS) ? acc * dinv[n] : 0.0f);
}

// ---- CSR agg layer2 (pre-scaled G2), unroll-8 + softmax -> out + fx16 ----
__global__ void __launch_bounds__(256) k_agg2c(const __hip_bfloat16* G, const int* cursor,
                                               const int* cnt, const int* csr, const float* dinv,
                                               const float* b2, float* outp, __hip_bfloat16* fx16) {
  int j = threadIdx.x & 31, g = threadIdx.x >> 5;
  int n = blockIdx.x * 8 + g;
  if (n >= N_NODES) return;
  int len = cnt[n];
  int st = cursor[n];
  float acc = bf2f(G[n * 32 + j]);
  int i = 0;
  for (; i + 8 <= len; i += 8) {
    int s[8];
    #pragma unroll
    for (int q = 0; q < 8; q++) s[q] = csr[st + i + q];
    float v[8];
    #pragma unroll
    for (int q = 0; q < 8; q++) v[q] = bf2f(G[s[q] * 32 + j]);
    #pragma unroll
    for (int q = 0; q < 8; q++) acc += v[q];
  }
  for (; i < len; i++) acc += bf2f(G[csr[st + i] * 32 + j]);
  bool act = (j < NCLUS);
  float logit = act ? fminf(fmaxf(dinv[n] * acc + b2[j], -80.0f), 80.0f) : -1e30f;
  float m = logit;
  #pragma unroll
  for (int mask = 16; mask > 0; mask >>= 1) m = fmaxf(m, __shfl_xor(m, mask, 32));
  float ex = act ? __expf(logit - m) : 0.0f;
  float ssum = ex;
  #pragma unroll
  for (int mask = 16; mask > 0; mask >>= 1) ssum += __shfl_xor(ssum, mask, 32);
  float fx = ex / fmaxf(ssum, 1e-30f);
  if (act) outp[n * NCLUS + j] = fx;
  fx16[n * 32 + j] = __float2bfloat16(act ? fx : 0.0f);
}

// ---- fallback fp32 kernels (atomic path) ----
__global__ void __launch_bounds__(256) k_gemm1s(const float* x, const float* W1,
                                                const float* dinv, float* G1) {
  __shared__ float Ws[IN_DIM * HID];
  int tid = threadIdx.x;
  for (int i = tid; i < IN_DIM * HID; i += 256) Ws[i] = W1[i];
  __syncthreads();
  int j = tid & 31, r = tid >> 5;
  int n = blockIdx.x * 8 + r;
  if (n >= N_NODES) return;
  const float* xr = x + (size_t)n * IN_DIM;
  float acc = 0.0f;
  #pragma unroll
  for (int k = 0; k < IN_DIM; k++) acc += xr[k] * Ws[k * HID + j];
  G1[n * 32 + j] = acc * dinv[n];
}

__global__ void __launch_bounds__(256) k_gemm2s(const float* h, const float* W2,
                                                const float* dinv, float* G2) {
  __shared__ float Ws[HID * 32];
  int tid = threadIdx.x;
  for (int i = tid; i < HID * 32; i += 256) Ws[i] = 0.0f;
  __syncthreads();
  for (int i = tid; i < HID * NCLUS; i += 256) {
    int k = i / NCLUS, j = i % NCLUS;
    Ws[k * 32 + j] = W2[i];
  }
  __syncthreads();
  int j = tid & 31, r = tid >> 5;
  int n = blockIdx.x * 8 + r;
  if (n >= N_NODES) return;
  const float* hr = h + (size_t)n * 32;
  float acc = 0.0f;
  #pragma unroll
  for (int k = 0; k < HID; k++) acc += hr[k] * Ws[k * 32 + j];
  G2[n * 32 + j] = (j < NCLUS) ? acc * dinv[n] : 0.0f;
}

__global__ void __launch_bounds__(256) k_eagg2(const int* ei, const int* flag,
                                               const float* G, float* D) {
  int j = threadIdx.x & 31, g = threadIdx.x >> 5;
  int f = *flag;
  for (int e = blockIdx.x * 8 + g; e < N_EDGES; e += gridDim.x * 8) {
    int s = edge_at(ei, 0, e, f);
    int d = edge_at(ei, 1, e, f);
    atomicAdd(&D[d * 32 + j], G[s * 32 + j]);
  }
}

__global__ void k_relu2(const float* A, const float* dinv, const float* b1, float* G) {
  int t = blockIdx.x * blockDim.x + threadIdx.x;
  if (t >= N_NODES * 32) return;
  int n = t >> 5, j = t & 31;
  G[t] = fmaxf(dinv[n] * (A[t] + G[t]) + b1[j], 0.0f);
}

__global__ void __launch_bounds__(256) k_softmax2(const float* S, const float* G2, const float* dinv,
                                                  const float* b2, float* outp) {
  int n = blockIdx.x * blockDim.x + threadIdx.x;
  if (n >= N_NODES) return;
  float di = dinv[n];
  float lg[NCLUS];
  float m = -1e30f;
  #pragma unroll
  for (int j = 0; j < NCLUS; j++) {
    float v = di * (S[n * 32 + j] + G2[n * 32 + j]) + b2[j];
    v = fminf(fmaxf(v, -80.0f), 80.0f);
    lg[j] = v; m = fmaxf(m, v);
  }
  float ssum = 0.0f;
  #pragma unroll
  for (int j = 0; j < NCLUS; j++) { lg[j] = __expf(lg[j] - m); ssum += lg[j]; }
  float inv = 1.0f / ssum;
  #pragma unroll
  for (int j = 0; j < NCLUS; j++) outp[n * NCLUS + j] = lg[j] * inv;
}

// ---- out (fp32, stride 30) -> fx16 (bf16, stride 32) ----
__global__ void k_fx16(const float* outp, __hip_bfloat16* fx16) {
  int t = blockIdx.x * blockDim.x + threadIdx.x;
  if (t >= N_NODES * 32) return;
  int n = t >> 5, j = t & 31;
  fx16[t] = __float2bfloat16((j < NCLUS) ? outp[n * NCLUS + j] : 0.0f);
}

// ---- edge MSE, lane-per-edge: in-lane packed-bf16 dot over 64B rows ----
__global__ void __launch_bounds__(256) k_msef2(const int* ei, const float* ep,
                                               const uint4* fx16, const int* flag,
                                               double* msed) {
  int f = *flag;
  int tid = blockIdx.x * blockDim.x + threadIdx.x;
  float local = 0.0f;
  for (int e = tid; e < N_EDGES; e += gridDim.x * blockDim.x) {
    int s = edge_at(ei, 0, e, f);
    int d = edge_at(ei, 1, e, f);
    const uint4* rs = fx16 + s * 4;
    const uint4* rd = fx16 + d * 4;
    uint4 a0 = rs[0], a1 = rs[1], a2 = rs[2], a3 = rs[3];
    uint4 b0 = rd[0], b1 = rd[1], b2 = rd[2], b3 = rd[3];
    float acc;
    acc  = dotw(a0.x, b0.x) + dotw(a0.y, b0.y) + dotw(a0.z, b0.z) + dotw(a0.w, b0.w);
    acc += dotw(a1.x, b1.x) + dotw(a1.y, b1.y) + dotw(a1.z, b1.z) + dotw(a1.w, b1.w);
    acc += dotw(a2.x, b2.x) + dotw(a2.y, b2.y) + dotw(a2.z, b2.z) + dotw(a2.w, b2.w);
    acc += dotw(a3.x, b3.x) + dotw(a3.y, b3.y) + dotw(a3.z, b3.z) + dotw(a3.w, b3.w);
    float diff = acc - ep[e];
    local += diff * diff;
  }
  __shared__ float sd[256];
  sd[threadIdx.x] = local; __syncthreads();
  for (int off = 128; off > 0; off >>= 1) {
    if (threadIdx.x < off) sd[threadIdx.x] += sd[threadIdx.x + off];
    __syncthreads();
  }
  if (threadIdx.x == 0) atomicAdd(msed, (double)sd[0]);
}

// ---- column sums of log(1-FX^2) ----
__global__ void __launch_bounds__(256) k_colsumf(const float* FX, float* colsum) {
  __shared__ float sd[256];
  int tid = threadIdx.x;
  int j = tid & 31, g = tid >> 5;
  float local = 0.0f;
  if (j < NCLUS) {
    for (int n = blockIdx.x * 8 + g; n < N_NODES; n += gridDim.x * 8) {
      float v = FX[n * NCLUS + j];
      local += log1pf(-v * v);
    }
  }
  sd[tid] = local; __syncthreads();
  if (tid < 32) {
    float s = 0.0f;
    #pragma unroll
    for (int gg = 0; gg < 8; gg++) s += sd[tid + 32 * gg];
    if (tid < NCLUS) atomicAdd(&colsum[tid], s);
  }
}

// ---- final loss ----
__global__ void k_final(const float* colsum, const double* msed, float* out) {
  int tid = threadIdx.x;
  float v = 0.0f;
  if (tid < NCLUS) v = logf(1.0001f - __expf(colsum[tid]));
  #pragma unroll
  for (int mask = 32; mask > 0; mask >>= 1) v += __shfl_xor(v, mask, 64);
  if (tid == 0) {
    float preg = -v;
    float msev = (float)(*msed / (double)N_EDGES);
    out[(size_t)N_NODES * NCLUS] = msev + 0.01f * preg;
  }
}

extern "C" void kernel_launch(void* const* d_in, const int* in_sizes, int n_in,
                              void* d_out, int out_size, void* d_ws, size_t ws_size,
                              hipStream_t stream) {
  const float* x  = (const float*)d_in[0];
  const int*   ei = (const int*)d_in[1];
  const float* ep = (const float*)d_in[2];
  const float* W1 = (const float*)d_in[3];
  const float* b1 = (const float*)d_in[4];
  const float* W2 = (const float*)d_in[5];
  const float* b2 = (const float*)d_in[6];
  float* out = (float*)d_out;   // fp32: FX[100000*30] then loss scalar

  char* ws = (char*)d_ws;
  size_t off = 0;
  auto alloc = [&](size_t bytes) { size_t o = off; off += (bytes + 255) & ~(size_t)255; return o; };

  size_t o_hdr  = alloc(1024);                       // flag@0, msed@8(double), colsum@256, bsum@512
  size_t o_cnt  = alloc((size_t)N_NODES * 4);
  size_t o_dinv = alloc((size_t)N_NODES * 4);
  size_t o_B1   = alloc((size_t)N_NODES * 32 * 4);   // CSR: G1b/G2b (bf16) ; fallback: fp32 G
  size_t o_B2   = alloc((size_t)N_NODES * 32 * 4);   // CSR: rank -> h fp32 -> fx16 ; fallback: fp32 D

  int*    flag   = (int*)(ws + o_hdr);
  double* msed   = (double*)(ws + o_hdr + 8);
  float*  colsum = (float*)(ws + o_hdr + 256);
  int*    bsum   = (int*)(ws + o_hdr + 512);
  int*    cnt    = (int*)(ws + o_cnt);
  float*  dinv   = (float*)(ws + o_dinv);
  float*  B1f    = (float*)(ws + o_B1);
  float*  B2f    = (float*)(ws + o_B2);
  __hip_bfloat16* B1b = (__hip_bfloat16*)(ws + o_B1);
  __hip_bfloat16* B2b = (__hip_bfloat16*)(ws + o_B2);

  const int nodeBlocks = (N_NODES + 255) / 256;
  const int edgeBlocks = EDGE_BLOCKS;
  const int grpBlocks  = GRP_BLOCKS;
  const int elemBlocks = (N_NODES * 32 + 255) / 256;

  k_detect<<<1, 64, 0, stream>>>((const unsigned int*)ei, flag);

  size_t o_cursor = alloc((size_t)N_NODES * 4);
  size_t o_csr    = alloc((size_t)N_EDGES * 4);
  bool use_csr = (off <= ws_size);   // confirmed running since R7 (ws >= 40.3 MB)

  const __hip_bfloat16* fx16;

  if (use_csr) {
    int* cursor = (int*)(ws + o_cursor);
    int* csr    = (int*)(ws + o_csr);
    int* rank   = (int*)(ws + o_B2);   // dead until agg1c writes h

    k_zero<<<1, 64, 0, stream>>>(colsum, msed);
    k_zerocnt<<<nodeBlocks, 256, 0, stream>>>(cnt);

    __hip_bfloat16* G1b  = B1b;
    // FUSED: count+rank (atomics) || gemm1 (unscaled) — co-scheduled
    k_fused1<<<edgeBlocks + grpBlocks, 256, 0, stream>>>(ei, flag, cnt, rank, x, W1, G1b);

    k_dinv<<<nodeBlocks, 256, 0, stream>>>(cnt, dinv);
    k_scan1<<<SCAN_NBLK, 256, 0, stream>>>(cnt, bsum);
    k_scan2<<<1, 64, 0, stream>>>(bsum);
    k_scan3<<<SCAN_NBLK, 256, 0, stream>>>(cnt, bsum, cursor);
    k_scatter2<<<edgeBlocks, 256, 0, stream>>>(ei, flag, cursor, rank, csr);

    float*          h    = B2f;        // overwrites rank (dead after scatter2)
    __hip_bfloat16* G2b  = B1b;        // reuse B1 (G1 dead after agg1c)
    __hip_bfloat16* fx   = B2b;        // reuse B2 (h dead after gemm2b)

    k_agg1c<<<grpBlocks, 256, 0, stream>>>(G1b, cursor, cnt, csr, dinv, b1, h);
    k_gemm2b<<<grpBlocks, 256, 0, stream>>>(h, W2, dinv, G2b);
    k_agg2c<<<grpBlocks, 256, 0, stream>>>(G2b, cursor, cnt, csr, dinv, b2, out, fx);
    fx16 = fx;
  } else {
    k_zero<<<1, 64, 0, stream>>>(colsum, msed);
    k_zerocnt<<<nodeBlocks, 256, 0, stream>>>(cnt);
    k_count<<<edgeBlocks, 256, 0, stream>>>(ei, flag, cnt);
    k_dinv<<<nodeBlocks, 256, 0, stream>>>(cnt, dinv);
    k_gemm1s<<<grpBlocks, 256, 0, stream>>>(x, W1, dinv, B1f);
    hipMemsetAsync(B2f, 0, (size_t)N_NODES * 32 * 4, stream);
    k_eagg2<<<8192, 256, 0, stream>>>(ei, flag, B1f, B2f);
    k_relu2<<<elemBlocks, 256, 0, stream>>>(B2f, dinv, b1, B1f);
    k_gemm2s<<<grpBlocks, 256, 0, stream>>>(B1f, W2, dinv, B2f);
    hipMemsetAsync(B1f, 0, (size_t)N_NODES * 32 * 4, stream);
    k_eagg2<<<8192, 256, 0, stream>>>(ei, flag, B2f, B1f);
    k_softmax2<<<nodeBlocks, 256, 0, stream>>>(B1f, B2f, dinv, b2, out);
    k_fx16<<<elemBlocks, 256, 0, stream>>>(out, B1b);
    fx16 = B1b;
  }

  // loss
  k_msef2<<<4096, 256, 0, stream>>>(ei, ep, (const uint4*)fx16, flag, msed);
  k_colsumf<<<256, 256, 0, stream>>>(out, colsum);
  k_final<<<1, 64, 0, stream>>>(colsum, msed, out);
}

// Round 13
// 602.158 us; speedup vs baseline: 1.0939x; 1.0720x over previous
//
#include <hip/hip_runtime.h>
#include <hip/hip_bf16.h>
#include <hip/hip_fp8.h>

#define N_NODES 100000
#define N_EDGES 3200000
#define IN_DIM  128
#define HID     32
#define NCLUS   30
#define SCAN_CHUNK 1024
#define SCAN_NBLK  98     // ceil(100000/1024)
#define EDGE_BLOCKS 12500 // ceil(3200000/256)
#define GRP_BLOCKS  12500 // ceil(100000/8)

__device__ __forceinline__ float bf2f(__hip_bfloat16 v) { return __bfloat162float(v); }

// fp8 e4m3 (OCP) encode/decode via HW cvt
__device__ __forceinline__ unsigned char enc8(float v) {
  __hip_fp8_e4m3 t(v); return (unsigned char)t.__x;
}
__device__ __forceinline__ float dec8(unsigned b) {
  __hip_fp8_e4m3 t; t.__x = (__hip_fp8_storage_t)b; return (float)t;
}
__device__ __forceinline__ float dot4_fp8(unsigned a, unsigned b) {
  float r = 0.0f;
  #pragma unroll
  for (int k = 0; k < 4; k++)
    r += dec8((a >> (8 * k)) & 0xffu) * dec8((b >> (8 * k)) & 0xffu);
  return r;
}

// edge_index accessor: f=0 -> int32 layout, f=1 -> int64 layout (read low word)
__device__ __forceinline__ int edge_at(const int* ei, int row, int e, int f) {
  int v = ei[(row * N_EDGES + e) << f];
  return min(max(v, 0), N_NODES - 1);
}

// ---- detect int32 vs int64 edge_index ----
__global__ void k_detect(const unsigned int* ei, int* flag) {
  if (threadIdx.x == 0) {
    int zeros = 0;
    for (int i = 1; i < 128; i += 2) zeros += (ei[i] == 0u) ? 1 : 0;
    *flag = (zeros >= 48) ? 1 : 0;
  }
}

// ---- zero loss scalars ----
__global__ void k_zero(float* colsum, double* msed) {
  int t = blockIdx.x * blockDim.x + threadIdx.x;
  if (t < 32) colsum[t] = 0.0f;
  if (t == 32) *msed = 0.0;
}

__global__ void k_zerocnt(int* cnt) {
  int t = blockIdx.x * blockDim.x + threadIdx.x;
  if (t < N_NODES) cnt[t] = 0;
}

// ---- FUSED, INTERLEAVED: even blocks -> count+rank chunk (blockIdx>>1);
//      odd blocks -> unscaled GEMM1 chunk (blockIdx>>1).
//      Parity interleave => both roles co-resident on every CU from dispatch start,
//      so gemm VALU/mem work issues while edge waves stall on atomic acks. ----
__global__ void __launch_bounds__(256) k_fused1(const int* ei, const int* flag, int* cnt, int* rank,
                                                const float* x, const float* W1, __hip_bfloat16* G1) {
  __shared__ float Ws[IN_DIM * HID];   // 16 KB (gemm half only)
  unsigned idx = blockIdx.x >> 1;
  if ((blockIdx.x & 1) == 0) {
    int e = idx * 256 + threadIdx.x;
    if (e < N_EDGES) {
      int f = *flag;
      int d = edge_at(ei, 1, e, f);
      rank[e] = atomicAdd(&cnt[d], 1);
    }
    return;
  }
  int tid = threadIdx.x;
  for (int i = tid; i < IN_DIM * HID; i += 256) Ws[i] = W1[i];
  __syncthreads();
  int j = tid & 31, r = tid >> 5;
  int n = idx * 8 + r;
  if (n >= N_NODES) return;
  const float* xr = x + (size_t)n * IN_DIM;
  float acc = 0.0f;
  #pragma unroll
  for (int k = 0; k < IN_DIM; k++) acc += xr[k] * Ws[k * HID + j];
  G1[n * 32 + j] = __float2bfloat16(acc);   // UNSCALED (dinv applied at gather)
}

// ---- plain count (fallback path) ----
__global__ void k_count(const int* ei, const int* flag, int* cnt) {
  int e = blockIdx.x * blockDim.x + threadIdx.x;
  if (e >= N_EDGES) return;
  int f = *flag;
  atomicAdd(&cnt[edge_at(ei, 1, e, f)], 1);
}

// ---- dinv ----
__global__ void k_dinv(const int* cnt, float* dinv) {
  int t = blockIdx.x * blockDim.x + threadIdx.x;
  if (t < N_NODES) dinv[t] = rsqrtf((float)(cnt[t] + 1));
}

// ---- scan stage 1 ----
__global__ void k_scan1(const int* cnt, int* bsum) {
  __shared__ int sd[256];
  int tid = threadIdx.x;
  int base = blockIdx.x * SCAN_CHUNK;
  int s = 0;
  for (int i = tid; i < SCAN_CHUNK; i += 256) {
    int idx = base + i;
    s += (idx < N_NODES) ? cnt[idx] : 0;
  }
  sd[tid] = s; __syncthreads();
  for (int off = 128; off > 0; off >>= 1) {
    if (tid < off) sd[tid] += sd[tid + off];
    __syncthreads();
  }
  if (tid == 0) bsum[blockIdx.x] = sd[0];
}

// ---- scan stage 2 ----
__global__ void k_scan2(int* bsum) {
  if (threadIdx.x == 0) {
    int run = 0;
    for (int i = 0; i < SCAN_NBLK; i++) { int t = bsum[i]; bsum[i] = run; run += t; }
  }
}

// ---- scan stage 3: cursor = exclusive prefix (row START) ----
__global__ void k_scan3(const int* cnt, const int* bsum, int* cursor) {
  __shared__ int ts[256];
  int tid = threadIdx.x;
  int base = blockIdx.x * SCAN_CHUNK + tid * 4;
  int v[4]; int s = 0;
  #pragma unroll
  for (int j = 0; j < 4; j++) {
    int idx = base + j;
    v[j] = (idx < N_NODES) ? cnt[idx] : 0;
    s += v[j];
  }
  ts[tid] = s; __syncthreads();
  for (int off = 1; off < 256; off <<= 1) {
    int t = (tid >= off) ? ts[tid - off] : 0;
    __syncthreads();
    ts[tid] += t;
    __syncthreads();
  }
  int excl = bsum[blockIdx.x] + (tid > 0 ? ts[tid - 1] : 0);
  #pragma unroll
  for (int j = 0; j < 4; j++) {
    int idx = base + j;
    if (idx < N_NODES) { cursor[idx] = excl; excl += v[j]; }
  }
}

// ---- CSR scatter, atomic-free ----
__global__ void k_scatter2(const int* ei, const int* flag, const int* cursor,
                           const int* rank, int* csr_src) {
  int e = blockIdx.x * blockDim.x + threadIdx.x;
  if (e >= N_EDGES) return;
  int f = *flag;
  int s = edge_at(ei, 0, e, f);
  int d = edge_at(ei, 1, e, f);
  csr_src[cursor[d] + rank[e]] = s;
}

// ---- CSR agg layer1, unroll-8, dinv[s]-weighted gather (G1 unscaled) ----
__global__ void __launch_bounds__(256) k_agg1c(const __hip_bfloat16* G, const int* cursor,
                                               const int* cnt, const int* csr, const float* dinv,
                                               const float* b1, float* h) {
  int j = threadIdx.x & 31, g = threadIdx.x >> 5;
  int n = blockIdx.x * 8 + g;
  if (n >= N_NODES) return;
  int len = cnt[n];
  int st = cursor[n];
  float dn = dinv[n];
  float acc = bf2f(G[n * 32 + j]) * dn;   // self loop
  int i = 0;
  for (; i + 8 <= len; i += 8) {
    int s[8];
    #pragma unroll
    for (int q = 0; q < 8; q++) s[q] = csr[st + i + q];
    float v[8], w[8];
    #pragma unroll
    for (int q = 0; q < 8; q++) { v[q] = bf2f(G[s[q] * 32 + j]); w[q] = dinv[s[q]]; }
    #pragma unroll
    for (int q = 0; q < 8; q++) acc += v[q] * w[q];
  }
  for (; i < len; i++) { int s0 = csr[st + i]; acc += bf2f(G[s0 * 32 + j]) * dinv[s0]; }
  h[n * 32 + j] = fmaxf(dn * acc + b1[j], 0.0f);
}

// ---- GEMM2 scaled -> bf16; cols 30,31 = 0 ----
__global__ void __launch_bounds__(256) k_gemm2b(const float* h, const float* W2,
                                                const float* dinv, __hip_bfloat16* G2) {
  __shared__ float Ws[HID * 32];
  int tid = threadIdx.x;
  for (int i = tid; i < HID * 32; i += 256) Ws[i] = 0.0f;
  __syncthreads();
  for (int i = tid; i < HID * NCLUS; i += 256) {
    int k = i / NCLUS, j = i % NCLUS;
    Ws[k * 32 + j] = W2[i];
  }
  __syncthreads();
  int j = tid & 31, r = tid >> 5;
  int n = blockIdx.x * 8 + r;
  if (n >= N_NODES) return;
  const float* hr = h + (size_t)n * 32;
  float acc = 0.0f;
  #pragma unroll
  for (int k = 0; k < HID; k++) acc += hr[k] * Ws[k * 32 + j];
  G2[n * 32 + j] = __float2bfloat16((j < NCLUS) ? acc * dinv[n] : 0.0f);
}

// ---- CSR agg layer2 (pre-scaled G2), unroll-8 + softmax -> out + fx8 (fp8, 32-padded) ----
__global__ void __launch_bounds__(256) k_agg2c(const __hip_bfloat16* G, const int* cursor,
                                               const int* cnt, const int* csr, const float* dinv,
                                               const float* b2, float* outp, unsigned char* fx8) {
  int j = threadIdx.x & 31, g = threadIdx.x >> 5;
  int n = blockIdx.x * 8 + g;
  if (n >= N_NODES) return;
  int len = cnt[n];
  int st = cursor[n];
  float acc = bf2f(G[n * 32 + j]);
  int i = 0;
  for (; i + 8 <= len; i += 8) {
    int s[8];
    #pragma unroll
    for (int q = 0; q < 8; q++) s[q] = csr[st + i + q];
    float v[8];
    #pragma unroll
    for (int q = 0; q < 8; q++) v[q] = bf2f(G[s[q] * 32 + j]);
    #pragma unroll
    for (int q = 0; q < 8; q++) acc += v[q];
  }
  for (; i < len; i++) acc += bf2f(G[csr[st + i] * 32 + j]);
  bool act = (j < NCLUS);
  float logit = act ? fminf(fmaxf(dinv[n] * acc + b2[j], -80.0f), 80.0f) : -1e30f;
  float m = logit;
  #pragma unroll
  for (int mask = 16; mask > 0; mask >>= 1) m = fmaxf(m, __shfl_xor(m, mask, 32));
  float ex = act ? __expf(logit - m) : 0.0f;
  float ssum = ex;
  #pragma unroll
  for (int mask = 16; mask > 0; mask >>= 1) ssum += __shfl_xor(ssum, mask, 32);
  float fx = ex / fmaxf(ssum, 1e-30f);
  if (act) outp[n * NCLUS + j] = fx;
  fx8[n * 32 + j] = enc8(act ? fx : 0.0f);
}

// ---- fallback fp32 kernels (atomic path) ----
__global__ void __launch_bounds__(256) k_gemm1s(const float* x, const float* W1,
                                                const float* dinv, float* G1) {
  __shared__ float Ws[IN_DIM * HID];
  int tid = threadIdx.x;
  for (int i = tid; i < IN_DIM * HID; i += 256) Ws[i] = W1[i];
  __syncthreads();
  int j = tid & 31, r = tid >> 5;
  int n = blockIdx.x * 8 + r;
  if (n >= N_NODES) return;
  const float* xr = x + (size_t)n * IN_DIM;
  float acc = 0.0f;
  #pragma unroll
  for (int k = 0; k < IN_DIM; k++) acc += xr[k] * Ws[k * HID + j];
  G1[n * 32 + j] = acc * dinv[n];
}

__global__ void __launch_bounds__(256) k_gemm2s(const float* h, const float* W2,
                                                const float* dinv, float* G2) {
  __shared__ float Ws[HID * 32];
  int tid = threadIdx.x;
  for (int i = tid; i < HID * 32; i += 256) Ws[i] = 0.0f;
  __syncthreads();
  for (int i = tid; i < HID * NCLUS; i += 256) {
    int k = i / NCLUS, j = i % NCLUS;
    Ws[k * 32 + j] = W2[i];
  }
  __syncthreads();
  int j = tid & 31, r = tid >> 5;
  int n = blockIdx.x * 8 + r;
  if (n >= N_NODES) return;
  const float* hr = h + (size_t)n * 32;
  float acc = 0.0f;
  #pragma unroll
  for (int k = 0; k < HID; k++) acc += hr[k] * Ws[k * 32 + j];
  G2[n * 32 + j] = (j < NCLUS) ? acc * dinv[n] : 0.0f;
}

__global__ void __launch_bounds__(256) k_eagg2(const int* ei, const int* flag,
                                               const float* G, float* D) {
  int j = threadIdx.x & 31, g = threadIdx.x >> 5;
  int f = *flag;
  for (int e = blockIdx.x * 8 + g; e < N_EDGES; e += gridDim.x * 8) {
    int s = edge_at(ei, 0, e, f);
    int d = edge_at(ei, 1, e, f);
    atomicAdd(&D[d * 32 + j], G[s * 32 + j]);
  }
}

__global__ void k_relu2(const float* A, const float* dinv, const float* b1, float* G) {
  int t = blockIdx.x * blockDim.x + threadIdx.x;
  if (t >= N_NODES * 32) return;
  int n = t >> 5, j = t & 31;
  G[t] = fmaxf(dinv[n] * (A[t] + G[t]) + b1[j], 0.0f);
}

__global__ void __launch_bounds__(256) k_softmax2(const float* S, const float* G2, const float* dinv,
                                                  const float* b2, float* outp) {
  int n = blockIdx.x * blockDim.x + threadIdx.x;
  if (n >= N_NODES) return;
  float di = dinv[n];
  float lg[NCLUS];
  float m = -1e30f;
  #pragma unroll
  for (int j = 0; j < NCLUS; j++) {
    float v = di * (S[n * 32 + j] + G2[n * 32 + j]) + b2[j];
    v = fminf(fmaxf(v, -80.0f), 80.0f);
    lg[j] = v; m = fmaxf(m, v);
  }
  float ssum = 0.0f;
  #pragma unroll
  for (int j = 0; j < NCLUS; j++) { lg[j] = __expf(lg[j] - m); ssum += lg[j]; }
  float inv = 1.0f / ssum;
  #pragma unroll
  for (int j = 0; j < NCLUS; j++) outp[n * NCLUS + j] = lg[j] * inv;
}

// ---- out (fp32, stride 30) -> fx8 (fp8, stride 32), fallback path ----
__global__ void k_fx8(const float* outp, unsigned char* fx8) {
  int t = blockIdx.x * blockDim.x + threadIdx.x;
  if (t >= N_NODES * 32) return;
  int n = t >> 5, j = t & 31;
  fx8[t] = enc8((j < NCLUS) ? outp[n * NCLUS + j] : 0.0f);
}

// ---- edge MSE, lane-per-edge over fp8 rows (32 B/row, L2-resident 3.2 MB table) ----
__global__ void __launch_bounds__(256) k_msef3(const int* ei, const float* ep,
                                               const uint4* fx8, const int* flag,
                                               double* msed) {
  int f = *flag;
  int tid = blockIdx.x * blockDim.x + threadIdx.x;
  float local = 0.0f;
  for (int e = tid; e < N_EDGES; e += gridDim.x * blockDim.x) {
    int s = edge_at(ei, 0, e, f);
    int d = edge_at(ei, 1, e, f);
    const uint4* rs = fx8 + s * 2;   // 32 B row = 2 x uint4
    const uint4* rd = fx8 + d * 2;
    uint4 a0 = rs[0], a1 = rs[1];
    uint4 b0 = rd[0], b1 = rd[1];
    float acc;
    acc  = dot4_fp8(a0.x, b0.x) + dot4_fp8(a0.y, b0.y)
         + dot4_fp8(a0.z, b0.z) + dot4_fp8(a0.w, b0.w);
    acc += dot4_fp8(a1.x, b1.x) + dot4_fp8(a1.y, b1.y)
         + dot4_fp8(a1.z, b1.z) + dot4_fp8(a1.w, b1.w);
    float diff = acc - ep[e];
    local += diff * diff;
  }
  __shared__ float sd[256];
  sd[threadIdx.x] = local; __syncthreads();
  for (int off = 128; off > 0; off >>= 1) {
    if (threadIdx.x < off) sd[threadIdx.x] += sd[threadIdx.x + off];
    __syncthreads();
  }
  if (threadIdx.x == 0) atomicAdd(msed, (double)sd[0]);
}

// ---- column sums of log(1-FX^2) ----
__global__ void __launch_bounds__(256) k_colsumf(const float* FX, float* colsum) {
  __shared__ float sd[256];
  int tid = threadIdx.x;
  int j = tid & 31, g = tid >> 5;
  float local = 0.0f;
  if (j < NCLUS) {
    for (int n = blockIdx.x * 8 + g; n < N_NODES; n += gridDim.x * 8) {
      float v = FX[n * NCLUS + j];
      local += log1pf(-v * v);
    }
  }
  sd[tid] = local; __syncthreads();
  if (tid < 32) {
    float s = 0.0f;
    #pragma unroll
    for (int gg = 0; gg < 8; gg++) s += sd[tid + 32 * gg];
    if (tid < NCLUS) atomicAdd(&colsum[tid], s);
  }
}

// ---- final loss ----
__global__ void k_final(const float* colsum, const double* msed, float* out) {
  int tid = threadIdx.x;
  float v = 0.0f;
  if (tid < NCLUS) v = logf(1.0001f - __expf(colsum[tid]));
  #pragma unroll
  for (int mask = 32; mask > 0; mask >>= 1) v += __shfl_xor(v, mask, 64);
  if (tid == 0) {
    float preg = -v;
    float msev = (float)(*msed / (double)N_EDGES);
    out[(size_t)N_NODES * NCLUS] = msev + 0.01f * preg;
  }
}

extern "C" void kernel_launch(void* const* d_in, const int* in_sizes, int n_in,
                              void* d_out, int out_size, void* d_ws, size_t ws_size,
                              hipStream_t stream) {
  const float* x  = (const float*)d_in[0];
  const int*   ei = (const int*)d_in[1];
  const float* ep = (const float*)d_in[2];
  const float* W1 = (const float*)d_in[3];
  const float* b1 = (const float*)d_in[4];
  const float* W2 = (const float*)d_in[5];
  const float* b2 = (const float*)d_in[6];
  float* out = (float*)d_out;   // fp32: FX[100000*30] then loss scalar

  char* ws = (char*)d_ws;
  size_t off = 0;
  auto alloc = [&](size_t bytes) { size_t o = off; off += (bytes + 255) & ~(size_t)255; return o; };

  size_t o_hdr  = alloc(1024);                       // flag@0, msed@8(double), colsum@256, bsum@512
  size_t o_cnt  = alloc((size_t)N_NODES * 4);
  size_t o_dinv = alloc((size_t)N_NODES * 4);
  size_t o_B1   = alloc((size_t)N_NODES * 32 * 4);   // CSR: G1b/G2b (bf16) ; fallback: fp32 G
  size_t o_B2   = alloc((size_t)N_NODES * 32 * 4);   // CSR: rank -> h fp32 -> fx8 ; fallback: fp32 D

  int*    flag   = (int*)(ws + o_hdr);
  double* msed   = (double*)(ws + o_hdr + 8);
  float*  colsum = (float*)(ws + o_hdr + 256);
  int*    bsum   = (int*)(ws + o_hdr + 512);
  int*    cnt    = (int*)(ws + o_cnt);
  float*  dinv   = (float*)(ws + o_dinv);
  float*  B1f    = (float*)(ws + o_B1);
  float*  B2f    = (float*)(ws + o_B2);
  __hip_bfloat16* B1b = (__hip_bfloat16*)(ws + o_B1);
  unsigned char*  B2c = (unsigned char*)(ws + o_B2);

  const int nodeBlocks = (N_NODES + 255) / 256;
  const int edgeBlocks = EDGE_BLOCKS;
  const int grpBlocks  = GRP_BLOCKS;
  const int elemBlocks = (N_NODES * 32 + 255) / 256;

  k_detect<<<1, 64, 0, stream>>>((const unsigned int*)ei, flag);

  size_t o_cursor = alloc((size_t)N_NODES * 4);
  size_t o_csr    = alloc((size_t)N_EDGES * 4);
  bool use_csr = (off <= ws_size);   // confirmed running since R7 (ws >= 40.3 MB)

  const unsigned char* fx8;

  if (use_csr) {
    int* cursor = (int*)(ws + o_cursor);
    int* csr    = (int*)(ws + o_csr);
    int* rank   = (int*)(ws + o_B2);   // dead until agg1c writes h

    k_zero<<<1, 64, 0, stream>>>(colsum, msed);
    k_zerocnt<<<nodeBlocks, 256, 0, stream>>>(cnt);

    __hip_bfloat16* G1b = B1b;
    // FUSED, parity-interleaved: count+rank || gemm1 co-resident on every CU
    k_fused1<<<edgeBlocks + grpBlocks, 256, 0, stream>>>(ei, flag, cnt, rank, x, W1, G1b);

    k_dinv<<<nodeBlocks, 256, 0, stream>>>(cnt, dinv);
    k_scan1<<<SCAN_NBLK, 256, 0, stream>>>(cnt, bsum);
    k_scan2<<<1, 64, 0, stream>>>(bsum);
    k_scan3<<<SCAN_NBLK, 256, 0, stream>>>(cnt, bsum, cursor);
    k_scatter2<<<edgeBlocks, 256, 0, stream>>>(ei, flag, cursor, rank, csr);

    float*          h   = B2f;         // overwrites rank (dead after scatter2)
    __hip_bfloat16* G2b = B1b;         // reuse B1 (G1 dead after agg1c)
    unsigned char*  fx  = B2c;         // reuse B2 (h dead after gemm2b)

    k_agg1c<<<grpBlocks, 256, 0, stream>>>(G1b, cursor, cnt, csr, dinv, b1, h);
    k_gemm2b<<<grpBlocks, 256, 0, stream>>>(h, W2, dinv, G2b);
    k_agg2c<<<grpBlocks, 256, 0, stream>>>(G2b, cursor, cnt, csr, dinv, b2, out, fx);
    fx8 = fx;
  } else {
    k_zero<<<1, 64, 0, stream>>>(colsum, msed);
    k_zerocnt<<<nodeBlocks, 256, 0, stream>>>(cnt);
    k_count<<<edgeBlocks, 256, 0, stream>>>(ei, flag, cnt);
    k_dinv<<<nodeBlocks, 256, 0, stream>>>(cnt, dinv);
    k_gemm1s<<<grpBlocks, 256, 0, stream>>>(x, W1, dinv, B1f);
    hipMemsetAsync(B2f, 0, (size_t)N_NODES * 32 * 4, stream);
    k_eagg2<<<8192, 256, 0, stream>>>(ei, flag, B1f, B2f);
    k_relu2<<<elemBlocks, 256, 0, stream>>>(B2f, dinv, b1, B1f);
    k_gemm2s<<<grpBlocks, 256, 0, stream>>>(B1f, W2, dinv, B2f);
    hipMemsetAsync(B1f, 0, (size_t)N_NODES * 32 * 4, stream);
    k_eagg2<<<8192, 256, 0, stream>>>(ei, flag, B2f, B1f);
    k_softmax2<<<nodeBlocks, 256, 0, stream>>>(B1f, B2f, dinv, b2, out);
    k_fx8<<<elemBlocks, 256, 0, stream>>>(out, (unsigned char*)B1b);
    fx8 = (const unsigned char*)B1b;
  }

  // loss
  k_msef3<<<4096, 256, 0, stream>>>(ei, ep, (const uint4*)fx8, flag, msed);
  k_colsumf<<<256, 256, 0, stream>>>(out, colsum);
  k_final<<<1, 64, 0, stream>>>(colsum, msed, out);
}

// Round 14
// 594.639 us; speedup vs baseline: 1.1077x; 1.0126x over previous
//
#include <hip/hip_runtime.h>
#include <hip/hip_bf16.h>
#include <hip/hip_fp8.h>

#define N_NODES 100000
#define N_EDGES 3200000
#define IN_DIM  128
#define HID     32
#define NCLUS   30
#define SCAN_CHUNK 1024
#define SCAN_NBLK  98     // ceil(100000/1024)
#define EDGE_BLOCKS 12500 // ceil(3200000/256)
#define GRP_BLOCKS  12500 // ceil(100000/8)
#define FUSE_BLOCKS 18750 // 6250 edge-chunks (512 edges) + 12500 gemm chunks

__device__ __forceinline__ float bf2f(__hip_bfloat16 v) { return __bfloat162float(v); }

// fp8 e4m3 (OCP) encode/decode via HW cvt
__device__ __forceinline__ unsigned char enc8(float v) {
  __hip_fp8_e4m3 t(v); return (unsigned char)t.__x;
}
__device__ __forceinline__ float dec8(unsigned b) {
  __hip_fp8_e4m3 t; t.__x = (__hip_fp8_storage_t)b; return (float)t;
}
__device__ __forceinline__ float dot4_fp8(unsigned a, unsigned b) {
  float r = 0.0f;
  #pragma unroll
  for (int k = 0; k < 4; k++)
    r += dec8((a >> (8 * k)) & 0xffu) * dec8((b >> (8 * k)) & 0xffu);
  return r;
}

// edge_index accessor: f=0 -> int32 layout, f=1 -> int64 layout (read low word)
__device__ __forceinline__ int edge_at(const int* ei, int row, int e, int f) {
  int v = ei[(row * N_EDGES + e) << f];
  return min(max(v, 0), N_NODES - 1);
}

// ---- detect int32 vs int64 edge_index ----
__global__ void k_detect(const unsigned int* ei, int* flag) {
  if (threadIdx.x == 0) {
    int zeros = 0;
    for (int i = 1; i < 128; i += 2) zeros += (ei[i] == 0u) ? 1 : 0;
    *flag = (zeros >= 48) ? 1 : 0;
  }
}

// ---- zero cnt + loss scalars (one launch) ----
__global__ void k_zeroall(int* cnt, float* colsum, double* msed) {
  int t = blockIdx.x * blockDim.x + threadIdx.x;
  if (t < N_NODES) cnt[t] = 0;
  if (t < 32) colsum[t] = 0.0f;
  if (t == 32) *msed = 0.0;
}

// ---- FUSED v3: no LDS; blockIdx%3==2 -> 512-edge count+rank chunk (2 edges/thread,
//      pipelined with-return atomics); else -> unscaled GEMM1 chunk via L1-cached W1. ----
__global__ void __launch_bounds__(256) k_fused1(const int* ei, const int* flag, int* cnt, int* rank,
                                                const float* x, const float* W1, __hip_bfloat16* G1) {
  unsigned g = blockIdx.x;
  unsigned t3 = g / 3;
  if (g % 3 == 2) {
    int f = *flag;
    int e0 = t3 * 512 + threadIdx.x;
    int e1 = e0 + 256;
    int d0 = -1, d1 = -1;
    if (e0 < N_EDGES) d0 = edge_at(ei, 1, e0, f);
    if (e1 < N_EDGES) d1 = edge_at(ei, 1, e1, f);
    int r0 = (d0 >= 0) ? atomicAdd(&cnt[d0], 1) : 0;   // two independent atomics in flight
    int r1 = (d1 >= 0) ? atomicAdd(&cnt[d1], 1) : 0;
    if (d0 >= 0) rank[e0] = r0;
    if (d1 >= 0) rank[e1] = r1;
    return;
  }
  unsigned gi = t3 * 2 + (g % 3);   // gemm chunk in [0, 12500)
  int j = threadIdx.x & 31, r = threadIdx.x >> 5;
  int n = gi * 8 + r;
  if (n >= N_NODES) return;
  const float* xr = x + (size_t)n * IN_DIM;
  float acc = 0.0f;
  #pragma unroll
  for (int k = 0; k < IN_DIM; k++) acc += xr[k] * W1[k * HID + j];  // W1 line L1-cached
  G1[n * 32 + j] = __float2bfloat16(acc);   // UNSCALED (dinv applied at gather)
}

// ---- plain count (fallback path) ----
__global__ void k_count(const int* ei, const int* flag, int* cnt) {
  int e = blockIdx.x * blockDim.x + threadIdx.x;
  if (e >= N_EDGES) return;
  int f = *flag;
  atomicAdd(&cnt[edge_at(ei, 1, e, f)], 1);
}

// ---- dinv (fallback path) ----
__global__ void k_dinv(const int* cnt, float* dinv) {
  int t = blockIdx.x * blockDim.x + threadIdx.x;
  if (t < N_NODES) dinv[t] = rsqrtf((float)(cnt[t] + 1));
}

// ---- scan stage 1 (+ fused dinv) ----
__global__ void k_scan1(const int* cnt, int* bsum, float* dinv) {
  __shared__ int sd[256];
  int tid = threadIdx.x;
  int base = blockIdx.x * SCAN_CHUNK;
  int s = 0;
  for (int i = tid; i < SCAN_CHUNK; i += 256) {
    int idx = base + i;
    int c = (idx < N_NODES) ? cnt[idx] : 0;
    if (idx < N_NODES) dinv[idx] = rsqrtf((float)(c + 1));
    s += c;
  }
  sd[tid] = s; __syncthreads();
  for (int off = 128; off > 0; off >>= 1) {
    if (tid < off) sd[tid] += sd[tid + off];
    __syncthreads();
  }
  if (tid == 0) bsum[blockIdx.x] = sd[0];
}

// ---- scan stage 2 ----
__global__ void k_scan2(int* bsum) {
  if (threadIdx.x == 0) {
    int run = 0;
    for (int i = 0; i < SCAN_NBLK; i++) { int t = bsum[i]; bsum[i] = run; run += t; }
  }
}

// ---- scan stage 3: cursor = exclusive prefix (row START) ----
__global__ void k_scan3(const int* cnt, const int* bsum, int* cursor) {
  __shared__ int ts[256];
  int tid = threadIdx.x;
  int base = blockIdx.x * SCAN_CHUNK + tid * 4;
  int v[4]; int s = 0;
  #pragma unroll
  for (int j = 0; j < 4; j++) {
    int idx = base + j;
    v[j] = (idx < N_NODES) ? cnt[idx] : 0;
    s += v[j];
  }
  ts[tid] = s; __syncthreads();
  for (int off = 1; off < 256; off <<= 1) {
    int t = (tid >= off) ? ts[tid - off] : 0;
    __syncthreads();
    ts[tid] += t;
    __syncthreads();
  }
  int excl = bsum[blockIdx.x] + (tid > 0 ? ts[tid - 1] : 0);
  #pragma unroll
  for (int j = 0; j < 4; j++) {
    int idx = base + j;
    if (idx < N_NODES) { cursor[idx] = excl; excl += v[j]; }
  }
}

// ---- CSR scatter, atomic-free ----
__global__ void k_scatter2(const int* ei, const int* flag, const int* cursor,
                           const int* rank, int* csr_src) {
  int e = blockIdx.x * blockDim.x + threadIdx.x;
  if (e >= N_EDGES) return;
  int f = *flag;
  int s = edge_at(ei, 0, e, f);
  int d = edge_at(ei, 1, e, f);
  csr_src[cursor[d] + rank[e]] = s;
}

// ---- FUSED agg1 + gemm2: gather G1 (unscaled, dinv[s]-weighted) -> h in reg ->
//      G2[n,j] = (sum_k shfl(h,k)*W2[k,j]) * dinv[n], bf16 out; h never touches memory ----
__global__ void __launch_bounds__(256) k_agg1f(const __hip_bfloat16* G, const int* cursor,
                                               const int* cnt, const int* csr, const float* dinv,
                                               const float* b1, const float* W2,
                                               __hip_bfloat16* G2) {
  int j = threadIdx.x & 31, g = threadIdx.x >> 5;
  int n = blockIdx.x * 8 + g;
  if (n >= N_NODES) return;
  float w2c[HID];
  #pragma unroll
  for (int k = 0; k < HID; k++) w2c[k] = (j < NCLUS) ? W2[k * NCLUS + j] : 0.0f;
  int len = cnt[n];
  int st = cursor[n];
  float dn = dinv[n];
  float acc = bf2f(G[n * 32 + j]) * dn;   // self loop
  int i = 0;
  for (; i + 8 <= len; i += 8) {
    int s[8];
    #pragma unroll
    for (int q = 0; q < 8; q++) s[q] = csr[st + i + q];
    float v[8], w[8];
    #pragma unroll
    for (int q = 0; q < 8; q++) { v[q] = bf2f(G[s[q] * 32 + j]); w[q] = dinv[s[q]]; }
    #pragma unroll
    for (int q = 0; q < 8; q++) acc += v[q] * w[q];
  }
  for (; i < len; i++) { int s0 = csr[st + i]; acc += bf2f(G[s0 * 32 + j]) * dinv[s0]; }
  float h = fmaxf(dn * acc + b1[j], 0.0f);
  float g2 = 0.0f;
  #pragma unroll
  for (int k = 0; k < HID; k++) g2 += __shfl(h, k, 32) * w2c[k];
  G2[n * 32 + j] = __float2bfloat16((j < NCLUS) ? g2 * dn : 0.0f);
}

// ---- CSR agg layer2 (pre-scaled G2), unroll-8 + softmax -> out + fx8 (fp8, 32-padded) ----
__global__ void __launch_bounds__(256) k_agg2c(const __hip_bfloat16* G, const int* cursor,
                                               const int* cnt, const int* csr, const float* dinv,
                                               const float* b2, float* outp, unsigned char* fx8) {
  int j = threadIdx.x & 31, g = threadIdx.x >> 5;
  int n = blockIdx.x * 8 + g;
  if (n >= N_NODES) return;
  int len = cnt[n];
  int st = cursor[n];
  float acc = bf2f(G[n * 32 + j]);
  int i = 0;
  for (; i + 8 <= len; i += 8) {
    int s[8];
    #pragma unroll
    for (int q = 0; q < 8; q++) s[q] = csr[st + i + q];
    float v[8];
    #pragma unroll
    for (int q = 0; q < 8; q++) v[q] = bf2f(G[s[q] * 32 + j]);
    #pragma unroll
    for (int q = 0; q < 8; q++) acc += v[q];
  }
  for (; i < len; i++) acc += bf2f(G[csr[st + i] * 32 + j]);
  bool act = (j < NCLUS);
  float logit = act ? fminf(fmaxf(dinv[n] * acc + b2[j], -80.0f), 80.0f) : -1e30f;
  float m = logit;
  #pragma unroll
  for (int mask = 16; mask > 0; mask >>= 1) m = fmaxf(m, __shfl_xor(m, mask, 32));
  float ex = act ? __expf(logit - m) : 0.0f;
  float ssum = ex;
  #pragma unroll
  for (int mask = 16; mask > 0; mask >>= 1) ssum += __shfl_xor(ssum, mask, 32);
  float fx = ex / fmaxf(ssum, 1e-30f);
  if (act) outp[n * NCLUS + j] = fx;
  fx8[n * 32 + j] = enc8(act ? fx : 0.0f);
}

// ---- fallback fp32 kernels (atomic path) ----
__global__ void __launch_bounds__(256) k_gemm1s(const float* x, const float* W1,
                                                const float* dinv, float* G1) {
  __shared__ float Ws[IN_DIM * HID];
  int tid = threadIdx.x;
  for (int i = tid; i < IN_DIM * HID; i += 256) Ws[i] = W1[i];
  __syncthreads();
  int j = tid & 31, r = tid >> 5;
  int n = blockIdx.x * 8 + r;
  if (n >= N_NODES) return;
  const float* xr = x + (size_t)n * IN_DIM;
  float acc = 0.0f;
  #pragma unroll
  for (int k = 0; k < IN_DIM; k++) acc += xr[k] * Ws[k * HID + j];
  G1[n * 32 + j] = acc * dinv[n];
}

__global__ void __launch_bounds__(256) k_gemm2s(const float* h, const float* W2,
                                                const float* dinv, float* G2) {
  __shared__ float Ws[HID * 32];
  int tid = threadIdx.x;
  for (int i = tid; i < HID * 32; i += 256) Ws[i] = 0.0f;
  __syncthreads();
  for (int i = tid; i < HID * NCLUS; i += 256) {
    int k = i / NCLUS, j = i % NCLUS;
    Ws[k * 32 + j] = W2[i];
  }
  __syncthreads();
  int j = tid & 31, r = tid >> 5;
  int n = blockIdx.x * 8 + r;
  if (n >= N_NODES) return;
  const float* hr = h + (size_t)n * 32;
  float acc = 0.0f;
  #pragma unroll
  for (int k = 0; k < HID; k++) acc += hr[k] * Ws[k * 32 + j];
  G2[n * 32 + j] = (j < NCLUS) ? acc * dinv[n] : 0.0f;
}

__global__ void __launch_bounds__(256) k_eagg2(const int* ei, const int* flag,
                                               const float* G, float* D) {
  int j = threadIdx.x & 31, g = threadIdx.x >> 5;
  int f = *flag;
  for (int e = blockIdx.x * 8 + g; e < N_EDGES; e += gridDim.x * 8) {
    int s = edge_at(ei, 0, e, f);
    int d = edge_at(ei, 1, e, f);
    atomicAdd(&D[d * 32 + j], G[s * 32 + j]);
  }
}

__global__ void k_relu2(const float* A, const float* dinv, const float* b1, float* G) {
  int t = blockIdx.x * blockDim.x + threadIdx.x;
  if (t >= N_NODES * 32) return;
  int n = t >> 5, j = t & 31;
  G[t] = fmaxf(dinv[n] * (A[t] + G[t]) + b1[j], 0.0f);
}

__global__ void __launch_bounds__(256) k_softmax2(const float* S, const float* G2, const float* dinv,
                                                  const float* b2, float* outp) {
  int n = blockIdx.x * blockDim.x + threadIdx.x;
  if (n >= N_NODES) return;
  float di = dinv[n];
  float lg[NCLUS];
  float m = -1e30f;
  #pragma unroll
  for (int j = 0; j < NCLUS; j++) {
    float v = di * (S[n * 32 + j] + G2[n * 32 + j]) + b2[j];
    v = fminf(fmaxf(v, -80.0f), 80.0f);
    lg[j] = v; m = fmaxf(m, v);
  }
  float ssum = 0.0f;
  #pragma unroll
  for (int j = 0; j < NCLUS; j++) { lg[j] = __expf(lg[j] - m); ssum += lg[j]; }
  float inv = 1.0f / ssum;
  #pragma unroll
  for (int j = 0; j < NCLUS; j++) outp[n * NCLUS + j] = lg[j] * inv;
}

// ---- out (fp32, stride 30) -> fx8 (fp8, stride 32), fallback path ----
__global__ void k_fx8(const float* outp, unsigned char* fx8) {
  int t = blockIdx.x * blockDim.x + threadIdx.x;
  if (t >= N_NODES * 32) return;
  int n = t >> 5, j = t & 31;
  fx8[t] = enc8((j < NCLUS) ? outp[n * NCLUS + j] : 0.0f);
}

// ---- edge MSE, lane-per-edge over fp8 rows (32 B/row, L2-resident 3.2 MB table) ----
__global__ void __launch_bounds__(256) k_msef3(const int* ei, const float* ep,
                                               const uint4* fx8, const int* flag,
                                               double* msed) {
  int f = *flag;
  int tid = blockIdx.x * blockDim.x + threadIdx.x;
  float local = 0.0f;
  for (int e = tid; e < N_EDGES; e += gridDim.x * blockDim.x) {
    int s = edge_at(ei, 0, e, f);
    int d = edge_at(ei, 1, e, f);
    const uint4* rs = fx8 + s * 2;   // 32 B row = 2 x uint4
    const uint4* rd = fx8 + d * 2;
    uint4 a0 = rs[0], a1 = rs[1];
    uint4 b0 = rd[0], b1 = rd[1];
    float acc;
    acc  = dot4_fp8(a0.x, b0.x) + dot4_fp8(a0.y, b0.y)
         + dot4_fp8(a0.z, b0.z) + dot4_fp8(a0.w, b0.w);
    acc += dot4_fp8(a1.x, b1.x) + dot4_fp8(a1.y, b1.y)
         + dot4_fp8(a1.z, b1.z) + dot4_fp8(a1.w, b1.w);
    float diff = acc - ep[e];
    local += diff * diff;
  }
  __shared__ float sd[256];
  sd[threadIdx.x] = local; __syncthreads();
  for (int off = 128; off > 0; off >>= 1) {
    if (threadIdx.x < off) sd[threadIdx.x] += sd[threadIdx.x + off];
    __syncthreads();
  }
  if (threadIdx.x == 0) atomicAdd(msed, (double)sd[0]);
}

// ---- column sums of log(1-FX^2) ----
__global__ void __launch_bounds__(256) k_colsumf(const float* FX, float* colsum) {
  __shared__ float sd[256];
  int tid = threadIdx.x;
  int j = tid & 31, g = tid >> 5;
  float local = 0.0f;
  if (j < NCLUS) {
    for (int n = blockIdx.x * 8 + g; n < N_NODES; n += gridDim.x * 8) {
      float v = FX[n * NCLUS + j];
      local += log1pf(-v * v);
    }
  }
  sd[tid] = local; __syncthreads();
  if (tid < 32) {
    float s = 0.0f;
    #pragma unroll
    for (int gg = 0; gg < 8; gg++) s += sd[tid + 32 * gg];
    if (tid < NCLUS) atomicAdd(&colsum[tid], s);
  }
}

// ---- final loss ----
__global__ void k_final(const float* colsum, const double* msed, float* out) {
  int tid = threadIdx.x;
  float v = 0.0f;
  if (tid < NCLUS) v = logf(1.0001f - __expf(colsum[tid]));
  #pragma unroll
  for (int mask = 32; mask > 0; mask >>= 1) v += __shfl_xor(v, mask, 64);
  if (tid == 0) {
    float preg = -v;
    float msev = (float)(*msed / (double)N_EDGES);
    out[(size_t)N_NODES * NCLUS] = msev + 0.01f * preg;
  }
}

extern "C" void kernel_launch(void* const* d_in, const int* in_sizes, int n_in,
                              void* d_out, int out_size, void* d_ws, size_t ws_size,
                              hipStream_t stream) {
  const float* x  = (const float*)d_in[0];
  const int*   ei = (const int*)d_in[1];
  const float* ep = (const float*)d_in[2];
  const float* W1 = (const float*)d_in[3];
  const float* b1 = (const float*)d_in[4];
  const float* W2 = (const float*)d_in[5];
  const float* b2 = (const float*)d_in[6];
  float* out = (float*)d_out;   // fp32: FX[100000*30] then loss scalar

  char* ws = (char*)d_ws;
  size_t off = 0;
  auto alloc = [&](size_t bytes) { size_t o = off; off += (bytes + 255) & ~(size_t)255; return o; };

  size_t o_hdr  = alloc(1024);                       // flag@0, msed@8(double), colsum@256, bsum@512
  size_t o_cnt  = alloc((size_t)N_NODES * 4);
  size_t o_dinv = alloc((size_t)N_NODES * 4);
  size_t o_B1   = alloc((size_t)N_NODES * 32 * 4);   // CSR: G1b/G2b (bf16) ; fallback: fp32 G
  size_t o_B2   = alloc((size_t)N_NODES * 32 * 4);   // CSR: rank -> fx8 ; fallback: fp32 D

  int*    flag   = (int*)(ws + o_hdr);
  double* msed   = (double*)(ws + o_hdr + 8);
  float*  colsum = (float*)(ws + o_hdr + 256);
  int*    bsum   = (int*)(ws + o_hdr + 512);
  int*    cnt    = (int*)(ws + o_cnt);
  float*  dinv   = (float*)(ws + o_dinv);
  float*  B1f    = (float*)(ws + o_B1);
  float*  B2f    = (float*)(ws + o_B2);
  __hip_bfloat16* B1b = (__hip_bfloat16*)(ws + o_B1);
  unsigned char*  B2c = (unsigned char*)(ws + o_B2);

  const int nodeBlocks = (N_NODES + 255) / 256;
  const int edgeBlocks = EDGE_BLOCKS;
  const int grpBlocks  = GRP_BLOCKS;
  const int elemBlocks = (N_NODES * 32 + 255) / 256;

  k_detect<<<1, 64, 0, stream>>>((const unsigned int*)ei, flag);

  size_t o_cursor = alloc((size_t)N_NODES * 4);
  size_t o_csr    = alloc((size_t)N_EDGES * 4);
  bool use_csr = (off <= ws_size);   // confirmed running since R7 (ws >= 40.3 MB)

  const unsigned char* fx8;

  if (use_csr) {
    int* cursor = (int*)(ws + o_cursor);
    int* csr    = (int*)(ws + o_csr);
    int* rank   = (int*)(ws + o_B2);   // dead after scatter2; then B2 -> fx8

    k_zeroall<<<nodeBlocks, 256, 0, stream>>>(cnt, colsum, msed);

    __hip_bfloat16* G1b = B1b;
    // FUSED v3: no LDS; 2-edges/thread count+rank || L1-cached gemm1
    k_fused1<<<FUSE_BLOCKS, 256, 0, stream>>>(ei, flag, cnt, rank, x, W1, G1b);

    k_scan1<<<SCAN_NBLK, 256, 0, stream>>>(cnt, bsum, dinv);   // + fused dinv
    k_scan2<<<1, 64, 0, stream>>>(bsum);
    k_scan3<<<SCAN_NBLK, 256, 0, stream>>>(cnt, bsum, cursor);
    k_scatter2<<<edgeBlocks, 256, 0, stream>>>(ei, flag, cursor, rank, csr);

    __hip_bfloat16* G2b = B1b;         // reuse B1 (G1 dead after agg1f)
    unsigned char*  fx  = B2c;         // reuse B2 (rank dead after scatter2)

    k_agg1f<<<grpBlocks, 256, 0, stream>>>(G1b, cursor, cnt, csr, dinv, b1, W2, G2b);
    k_agg2c<<<grpBlocks, 256, 0, stream>>>(G2b, cursor, cnt, csr, dinv, b2, out, fx);
    fx8 = fx;
  } else {
    k_zeroall<<<nodeBlocks, 256, 0, stream>>>(cnt, colsum, msed);
    k_count<<<edgeBlocks, 256, 0, stream>>>(ei, flag, cnt);
    k_dinv<<<nodeBlocks, 256, 0, stream>>>(cnt, dinv);
    k_gemm1s<<<grpBlocks, 256, 0, stream>>>(x, W1, dinv, B1f);
    hipMemsetAsync(B2f, 0, (size_t)N_NODES * 32 * 4, stream);
    k_eagg2<<<8192, 256, 0, stream>>>(ei, flag, B1f, B2f);
    k_relu2<<<elemBlocks, 256, 0, stream>>>(B2f, dinv, b1, B1f);
    k_gemm2s<<<grpBlocks, 256, 0, stream>>>(B1f, W2, dinv, B2f);
    hipMemsetAsync(B1f, 0, (size_t)N_NODES * 32 * 4, stream);
    k_eagg2<<<8192, 256, 0, stream>>>(ei, flag, B2f, B1f);
    k_softmax2<<<nodeBlocks, 256, 0, stream>>>(B1f, B2f, dinv, b2, out);
    k_fx8<<<elemBlocks, 256, 0, stream>>>(out, (unsigned char*)B1b);
    fx8 = (const unsigned char*)B1b;
  }

  // loss
  k_msef3<<<4096, 256, 0, stream>>>(ei, ep, (const uint4*)fx8, flag, msed);
  k_colsumf<<<256, 256, 0, stream>>>(out, colsum);
  k_final<<<1, 64, 0, stream>>>(colsum, msed, out);
}